// Round 1
// baseline (4751.391 us; speedup 1.0000x reference)
//
#include <hip/hip_runtime.h>
#include <math.h>

// Problem constants
#define BQ   8
#define NFQ  4096
#define INQ  512
#define NBQ  2
#define NWQ  320
#define CDQ  384
#define MQ   (BQ*NFQ)              // 32768 rows
#define NTOT (NBQ*NWQ)             // 640
#define DMOD (NBQ*CDQ)             // 768
#define QOUT ((size_t)MQ*(size_t)DMOD)  // 25165824 -> perplexity slot

// GEMM tile config: block computes 64 rows x 320 cols (one codebook)
#define BM      64
#define KC      16
#define NCHUNK  (INQ/KC)           // 32
#define THREADS 256
#define TM      8                  // rows per thread
#define TN      10                 // cols per thread
#define XSS     68                 // padded x-tile row stride (floats)

// Shared memory layout (float offsets)
#define XS0 0
#define XS1 (KC*XSS)               // 1088
#define WT0 (2*KC*XSS)             // 2176
#define WT1 (WT0 + KC*NWQ)         // 7296
#define SMEM_F (WT1 + KC*NWQ)      // 12416 floats = 49664 B
// epilogue arrays alias WT0 region (parity-0; last chunk reads parity-1)
#define MARG WT0                   // [8][320] floats
#define IDXS_OFF (WT0 + 8*NWQ)     // 64 ints

__global__ __launch_bounds__(THREADS, 3) void qk1(
    const float* __restrict__ x, const float* __restrict__ W,
    const float* __restrict__ bias, const float* __restrict__ cb,
    const float* __restrict__ gum, const int* __restrict__ maskp,
    float* __restrict__ out, float* __restrict__ partial)
{
    __shared__ __align__(16) float smem[SMEM_F];
    const int tid = threadIdx.x;
    const int mb  = blockIdx.x;          // 0..511
    const int nb  = blockIdx.y;          // 0..1
    const int m0  = mb * BM;
    const int tn  = tid & 31;            // 0..31 -> cols tn*10..+9
    const int tm  = tid >> 5;            // 0..7  -> rows tm*8..+7

    // ---- staging address precompute ----
    int woff[5], wl[5];
#pragma unroll
    for (int j = 0; j < 5; ++j) {
        int l4 = tid + 256*j;            // float4 index into 16x320 tile
        int kk = l4 / 80;
        int c4 = l4 - kk*80;
        woff[j] = kk*NTOT + nb*NWQ + c4*4;   // float offset into W (chunk 0)
        wl[j]   = l4*4;                      // float offset into wt buffer
    }
    const int xr = tid >> 2;             // row 0..63
    const int xq = tid & 3;              // 16B quad 0..3
    const float* xg = x + (size_t)(m0 + xr)*INQ + xq*4;
    int xw[4];
#pragma unroll
    for (int u = 0; u < 4; ++u) xw[u] = (xq*4+u)*XSS + xr;

    float acc[TM][TN];
#pragma unroll
    for (int i = 0; i < TM; ++i)
#pragma unroll
        for (int j = 0; j < TN; ++j) acc[i][j] = 0.f;

    // prologue: stage chunk 0 into buffer 0
    {
        float4 wv[5];
#pragma unroll
        for (int j = 0; j < 5; ++j) wv[j] = *(const float4*)(W + woff[j]);
        float4 xv = *(const float4*)(xg);
#pragma unroll
        for (int j = 0; j < 5; ++j) *(float4*)(smem + WT0 + wl[j]) = wv[j];
#pragma unroll
        for (int u = 0; u < 4; ++u) smem[XS0 + xw[u]] = ((const float*)&xv)[u];
    }
    __syncthreads();

    for (int c = 0; c < NCHUNK; ++c) {
        const int buf = c & 1;
        const bool more = (c+1 < NCHUNK);
        float4 wv[5]; float4 xv;
        if (more) {                      // issue next-chunk global loads early
#pragma unroll
            for (int j = 0; j < 5; ++j)
                wv[j] = *(const float4*)(W + (size_t)(c+1)*(KC*NTOT) + woff[j]);
            xv = *(const float4*)(xg + (c+1)*KC);
        }
        const float* xb = smem + (buf ? XS1 : XS0);
        const float* wb = smem + (buf ? WT1 : WT0);
#pragma unroll
        for (int kk = 0; kk < KC; ++kk) {
            float a[TM], bb[TN];
            *(float4*)(a)   = *(const float4*)(xb + kk*XSS + tm*TM);
            *(float4*)(a+4) = *(const float4*)(xb + kk*XSS + tm*TM + 4);
#pragma unroll
            for (int u = 0; u < 5; ++u)
                *(float2*)(bb + 2*u) = *(const float2*)(wb + kk*NWQ + tn*TN + 2*u);
#pragma unroll
            for (int i = 0; i < TM; ++i)
#pragma unroll
                for (int j = 0; j < TN; ++j)
                    acc[i][j] = fmaf(a[i], bb[j], acc[i][j]);
        }
        if (more) {                      // write-late into the other buffer
            float* xo = smem + (buf ? XS0 : XS1);
            float* wo = smem + (buf ? WT0 : WT1);
#pragma unroll
            for (int j = 0; j < 5; ++j) *(float4*)(wo + wl[j]) = wv[j];
#pragma unroll
            for (int u = 0; u < 4; ++u) xo[xw[u]] = ((const float*)&xv)[u];
        }
        __syncthreads();
    }

    // ---- epilogue ----
    float bb2[TN];
#pragma unroll
    for (int u = 0; u < 5; ++u)
        *(float2*)(bb2 + 2*u) = *(const float2*)(bias + nb*NWQ + tn*TN + 2*u);
#pragma unroll
    for (int i = 0; i < TM; ++i)
#pragma unroll
        for (int j = 0; j < TN; ++j) acc[i][j] += bb2[j];

    int* idxs = (int*)(smem + IDXS_OFF);
    float colacc[TN];
#pragma unroll
    for (int j = 0; j < TN; ++j) colacc[j] = 0.f;

#pragma unroll
    for (int i = 0; i < TM; ++i) {
        const int r  = tm*TM + i;
        const int gm = m0 + r;
        // softmax denom (logits only) across the 32 lanes of this row group
        float mx = acc[i][0];
#pragma unroll
        for (int j = 1; j < TN; ++j) mx = fmaxf(mx, acc[i][j]);
#pragma unroll
        for (int s = 16; s >= 1; s >>= 1) mx = fmaxf(mx, __shfl_xor(mx, s, 32));
        float p[TN]; float se = 0.f;
#pragma unroll
        for (int j = 0; j < TN; ++j) { p[j] = __expf(acc[i][j] - mx); se += p[j]; }
#pragma unroll
        for (int s = 16; s >= 1; s >>= 1) se += __shfl_xor(se, s, 32);
        // gumbel argmax (y = logits + gumbel, TAU=1), first-index tie-break
        float gv[TN];
        const float* gp = gum + (size_t)gm*NTOT + nb*NWQ + tn*TN;
#pragma unroll
        for (int u = 0; u < 5; ++u) *(float2*)(gv + 2*u) = *(const float2*)(gp + 2*u);
        float ym = -3.0e38f; int yi = 0;
#pragma unroll
        for (int j = 0; j < TN; ++j) {
            float y = acc[i][j] + gv[j];
            if (y > ym) { ym = y; yi = tn*TN + j; }
        }
#pragma unroll
        for (int s = 16; s >= 1; s >>= 1) {
            float ov = __shfl_xor(ym, s, 32);
            int   oi = __shfl_xor(yi, s, 32);
            if (ov > ym || (ov == ym && oi < yi)) { ym = ov; yi = oi; }
        }
        if (tn == 0) idxs[r] = yi;
        // masked soft-prob accumulation (valid = mask==0)
        if (maskp[gm] == 0) {
            float inv = 1.0f / se;
#pragma unroll
            for (int j = 0; j < TN; ++j) colacc[j] += p[j] * inv;
        }
    }

    // per-block marginal partials -> workspace (deterministic, no atomics)
#pragma unroll
    for (int j = 0; j < TN; ++j) smem[MARG + tm*NWQ + tn*TN + j] = colacc[j];
    __syncthreads();
    for (int ccol = tid; ccol < NWQ; ccol += THREADS) {
        float s = 0.f;
#pragma unroll
        for (int g = 0; g < 8; ++g) s += smem[MARG + g*NWQ + ccol];
        partial[(size_t)mb*NTOT + nb*NWQ + ccol] = s;
    }

    // gather codebook rows -> quantized output
    const float* cbb = cb + (size_t)nb*NWQ*CDQ;
    for (int t = tid; t < BM*(CDQ/4); t += THREADS) {
        const int r = t / (CDQ/4);
        const int q = t - r*(CDQ/4);
        const int idx = idxs[r];
        float4 v = *(const float4*)(cbb + (size_t)idx*CDQ + q*4);
        *(float4*)(out + (size_t)(m0+r)*DMOD + (size_t)nb*CDQ + q*4) = v;
    }
}

// Reduce partials -> marginal -> perplexity
__global__ void qk2(const float* __restrict__ partial,
                    const int* __restrict__ maskp,
                    float* __restrict__ out)
{
    __shared__ int   ired[10];
    __shared__ float fred[10];
    __shared__ float s_ms;
    const int tid  = threadIdx.x;        // 0..639
    const int lane = tid & 63;
    const int wid  = tid >> 6;           // 0..9 (waves 0-4: nb0, 5-9: nb1)

    int ms = 0;
    for (int i = tid; i < MQ; i += 640) ms += maskp[i];
#pragma unroll
    for (int s = 32; s >= 1; s >>= 1) ms += __shfl_xor(ms, s, 64);
    if (lane == 0) ired[wid] = ms;
    __syncthreads();
    if (tid == 0) {
        int t = 0;
        for (int w = 0; w < 10; ++w) t += ired[w];
        s_ms = (float)t;
    }
    __syncthreads();

    float cs0 = 0.f, cs1 = 0.f, cs2 = 0.f, cs3 = 0.f;
    for (int mbq = 0; mbq < MQ/BM; mbq += 4) {
        cs0 += partial[(size_t)(mbq+0)*NTOT + tid];
        cs1 += partial[(size_t)(mbq+1)*NTOT + tid];
        cs2 += partial[(size_t)(mbq+2)*NTOT + tid];
        cs3 += partial[(size_t)(mbq+3)*NTOT + tid];
    }
    float cs = (cs0 + cs1) + (cs2 + cs3);
    float mar = cs / s_ms;
    float tv = mar * logf(mar + 1e-7f);
#pragma unroll
    for (int s = 32; s >= 1; s >>= 1) tv += __shfl_xor(tv, s, 64);
    if (lane == 0) fred[wid] = tv;
    __syncthreads();
    if (tid == 0) {
        float h0 = fred[0]+fred[1]+fred[2]+fred[3]+fred[4];
        float h1 = fred[5]+fred[6]+fred[7]+fred[8]+fred[9];
        out[QOUT] = expf(-h0) + expf(-h1);
    }
}

extern "C" void kernel_launch(void* const* d_in, const int* in_sizes, int n_in,
                              void* d_out, int out_size, void* d_ws, size_t ws_size,
                              hipStream_t stream) {
    const float* x    = (const float*)d_in[0];
    const float* W    = (const float*)d_in[1];
    const float* bias = (const float*)d_in[2];
    const float* cb   = (const float*)d_in[3];
    const float* gum  = (const float*)d_in[4];
    const int*   mask = (const int*)d_in[5];
    float* out = (float*)d_out;
    float* partial = (float*)d_ws;       // [512][640] f32 = 1.31 MB

    dim3 grid(MQ/BM, NBQ);
    qk1<<<grid, THREADS, 0, stream>>>(x, W, bias, cb, gum, mask, out, partial);
    qk2<<<1, 640, 0, stream>>>(partial, mask, out);
}